// Round 1
// baseline (147.751 us; speedup 1.0000x reference)
//
#include <hip/hip_runtime.h>

#define D_MODEL 256
#define N_ROWS (4 * 64 * 4 * 512)   // 524288 rows of D=256
#define LN_EPS 1e-5f

// One wave (64 lanes) per output row; each lane owns 4 consecutive d.
// Grid-stride over rows so per-lane weight constants amortize.
__global__ __launch_bounds__(256) void csi_encoder_kernel(
    const float* __restrict__ csi_real,
    const float* __restrict__ csi_imag,
    const float* __restrict__ w_c,      // [256,2] row-major
    const float* __restrict__ b_c,
    const float* __restrict__ w_s,
    const float* __restrict__ b_s,
    const float* __restrict__ w_u,
    const float* __restrict__ b_u,
    const float* __restrict__ w_f,
    const float* __restrict__ b_f,
    const float* __restrict__ ln_gamma,
    const float* __restrict__ ln_beta,
    float* __restrict__ out)
{
    const int lane = threadIdx.x & 63;
    const int waveInBlock = threadIdx.x >> 6;
    const int waveId = blockIdx.x * 4 + waveInBlock;
    const int nWaves = gridDim.x * 4;
    const int d0 = lane * 4;

    // Per-lane constants for d = d0..d0+3 (L1/L2-resident; loaded once per wave).
    float wc0[4], wc1[4], wsv[4], wuv[4], wfv[4], bsum[4], gv[4], bv[4];
#pragma unroll
    for (int j = 0; j < 4; ++j) {
        const int d = d0 + j;
        wc0[j]  = w_c[d * 2 + 0];
        wc1[j]  = w_c[d * 2 + 1];
        wsv[j]  = w_s[d];
        wuv[j]  = w_u[d];
        wfv[j]  = w_f[d];
        bsum[j] = b_c[d] + b_s[d] + b_u[d] + b_f[d];
        gv[j]   = ln_gamma[d];
        bv[j]   = ln_beta[d];
    }

    for (int r = waveId; r < N_ROWS; r += nWaves) {
        // r is both the flat CSI index and the row index of out.
        const float re = csi_real[r];
        const float im = csi_imag[r];
        const float scf = (float)(r & 511);
        const float uef = (float)((r >> 9) & 3);
        const float bsf = (float)((r >> 11) & 63);

        float v[4];
        float s = 0.0f, s2 = 0.0f;
#pragma unroll
        for (int j = 0; j < 4; ++j) {
            float t = bsum[j];
            t = fmaf(scf, wfv[j], t);
            t = fmaf(uef, wuv[j], t);
            t = fmaf(bsf, wsv[j], t);
            t = fmaf(im,  wc1[j], t);
            t = fmaf(re,  wc0[j], t);
            v[j] = t;
            s += t;
            s2 = fmaf(t, t, s2);
        }

        // Wave-wide butterfly reduction over 64 lanes (sum and sumsq together).
#pragma unroll
        for (int off = 32; off >= 1; off >>= 1) {
            s  += __shfl_xor(s,  off, 64);
            s2 += __shfl_xor(s2, off, 64);
        }

        const float mean = s * (1.0f / 256.0f);
        const float var  = fmaf(-mean, mean, s2 * (1.0f / 256.0f));
        const float rstd = rsqrtf(var + LN_EPS);

        float4 o;
        o.x = fmaf((v[0] - mean) * rstd, gv[0], bv[0]);
        o.y = fmaf((v[1] - mean) * rstd, gv[1], bv[1]);
        o.z = fmaf((v[2] - mean) * rstd, gv[2], bv[2]);
        o.w = fmaf((v[3] - mean) * rstd, gv[3], bv[3]);
        *reinterpret_cast<float4*>(out + (size_t)r * D_MODEL + d0) = o;
    }
}

extern "C" void kernel_launch(void* const* d_in, const int* in_sizes, int n_in,
                              void* d_out, int out_size, void* d_ws, size_t ws_size,
                              hipStream_t stream) {
    const float* csi_real = (const float*)d_in[0];
    const float* csi_imag = (const float*)d_in[1];
    const float* w_c      = (const float*)d_in[2];
    const float* b_c      = (const float*)d_in[3];
    const float* w_s      = (const float*)d_in[4];
    const float* b_s      = (const float*)d_in[5];
    const float* w_u      = (const float*)d_in[6];
    const float* b_u      = (const float*)d_in[7];
    const float* w_f      = (const float*)d_in[8];
    const float* b_f      = (const float*)d_in[9];
    const float* ln_gamma = (const float*)d_in[10];
    const float* ln_beta  = (const float*)d_in[11];
    float* out = (float*)d_out;

    const int blocks = 2048;   // 8192 waves; 64 rows per wave, grid-stride
    csi_encoder_kernel<<<blocks, 256, 0, stream>>>(
        csi_real, csi_imag, w_c, b_c, w_s, b_s, w_u, b_u, w_f, b_f,
        ln_gamma, ln_beta, out);
}

// Round 4
// 144.665 us; speedup vs baseline: 1.0213x; 1.0213x over previous
//
#include <hip/hip_runtime.h>

#define D_MODEL 256
#define N_ROWS (4 * 64 * 4 * 512)   // 524288 rows of D=256
#define LN_EPS 1e-5f

// ---------------------------------------------------------------------------
// Kernel A: one wave computes the 6x6 Gram matrix (and column means) of the
// per-d weight vectors a(d) = [wc0, wc1, ws, wu, wf, bsum], in double, so the
// main kernel can evaluate mean and E[x^2] per row in closed form.
// Output g[27] (all pre-divided by 256, cross terms pre-doubled):
//  0:rr 1:ii 2:2ri | 3..6: 2*r{B,U,S,1} | 7..10: 2*i{B,U,S,1}
//  11:BB 12:UU 13:SS 14:2BU 15:2BS 16:2US 17:2B 18:2U 19:2S 20:11
//  21..26: means of a_i
// ---------------------------------------------------------------------------
__global__ __launch_bounds__(64) void csi_gram_kernel(
    const float* __restrict__ w_c, const float* __restrict__ b_c,
    const float* __restrict__ w_s, const float* __restrict__ b_s,
    const float* __restrict__ w_u, const float* __restrict__ b_u,
    const float* __restrict__ w_f, const float* __restrict__ b_f,
    float* __restrict__ g)
{
    const int lane = threadIdx.x;
    double acc[27];
#pragma unroll
    for (int i = 0; i < 27; ++i) acc[i] = 0.0;

#pragma unroll
    for (int k = 0; k < 4; ++k) {
        const int d = lane + 64 * k;
        const double a0 = w_c[2 * d];
        const double a1 = w_c[2 * d + 1];
        const double a2 = w_s[d];
        const double a3 = w_u[d];
        const double a4 = w_f[d];
        const double a5 = (double)b_c[d] + (double)b_s[d] + (double)b_u[d] + (double)b_f[d];
        acc[0]  += a0 * a0;  acc[1]  += a1 * a1;  acc[2]  += a0 * a1;
        acc[3]  += a0 * a2;  acc[4]  += a0 * a3;  acc[5]  += a0 * a4;  acc[6]  += a0 * a5;
        acc[7]  += a1 * a2;  acc[8]  += a1 * a3;  acc[9]  += a1 * a4;  acc[10] += a1 * a5;
        acc[11] += a2 * a2;  acc[12] += a3 * a3;  acc[13] += a4 * a4;
        acc[14] += a2 * a3;  acc[15] += a2 * a4;  acc[16] += a3 * a4;
        acc[17] += a2 * a5;  acc[18] += a3 * a5;  acc[19] += a4 * a5;  acc[20] += a5 * a5;
        acc[21] += a0;  acc[22] += a1;  acc[23] += a2;
        acc[24] += a3;  acc[25] += a4;  acc[26] += a5;
    }

#pragma unroll
    for (int off = 32; off >= 1; off >>= 1) {
#pragma unroll
        for (int i = 0; i < 27; ++i) acc[i] += __shfl_xor(acc[i], off, 64);
    }

    if (lane == 0) {
        const double inv = 1.0 / 256.0;
        double r[27];
#pragma unroll
        for (int i = 0; i < 27; ++i) r[i] = acc[i] * inv;
        // Cross terms doubled — explicit, auditable list: {2..10, 14..19}.
        r[2]  *= 2.0; r[3]  *= 2.0; r[4]  *= 2.0; r[5]  *= 2.0; r[6]  *= 2.0;
        r[7]  *= 2.0; r[8]  *= 2.0; r[9]  *= 2.0; r[10] *= 2.0;
        r[14] *= 2.0; r[15] *= 2.0; r[16] *= 2.0;
        r[17] *= 2.0; r[18] *= 2.0; r[19] *= 2.0;
#pragma unroll
        for (int i = 0; i < 27; ++i) g[i] = (float)r[i];
    }
}

// ---------------------------------------------------------------------------
// Kernel B: pure streaming. One wave per row (64 lanes x 4 d each); mean and
// E[x^2] come from the closed form — no cross-lane ops, no LDS, no barriers.
// ---------------------------------------------------------------------------
__global__ __launch_bounds__(256) void csi_encoder_kernel(
    const float* __restrict__ csi_real,
    const float* __restrict__ csi_imag,
    const float* __restrict__ w_c,
    const float* __restrict__ b_c,
    const float* __restrict__ w_s,
    const float* __restrict__ b_s,
    const float* __restrict__ w_u,
    const float* __restrict__ b_u,
    const float* __restrict__ w_f,
    const float* __restrict__ b_f,
    const float* __restrict__ ln_gamma,
    const float* __restrict__ ln_beta,
    const float* __restrict__ g,       // 27 Gram/mean constants
    float* __restrict__ out)
{
    const int lane = threadIdx.x & 63;
    const int waveId = blockIdx.x * 4 + (threadIdx.x >> 6);
    const int nWaves = gridDim.x * 4;
    const int d0 = lane * 4;

    // Per-lane (per-d) constants, loaded once per wave.
    float wc0[4], wc1[4], wsv[4], wuv[4], wfv[4], bsum[4], gv[4], bv[4];
#pragma unroll
    for (int j = 0; j < 4; ++j) {
        const int d = d0 + j;
        wc0[j]  = w_c[d * 2 + 0];
        wc1[j]  = w_c[d * 2 + 1];
        wsv[j]  = w_s[d];
        wuv[j]  = w_u[d];
        wfv[j]  = w_f[d];
        bsum[j] = b_c[d] + b_s[d] + b_u[d] + b_f[d];
        gv[j]   = ln_gamma[d];
        bv[j]   = ln_beta[d];
    }

    // Wave-uniform Gram constants (uniform addresses -> scalar loads).
    float G[27];
#pragma unroll
    for (int i = 0; i < 27; ++i) G[i] = g[i];

    for (int r = waveId; r < N_ROWS; r += nWaves) {
        const float re = csi_real[r];
        const float im = csi_imag[r];
        const float fS = (float)(r & 511);          // subcarrier index
        const float fU = (float)((r >> 9) & 3);     // UE antenna index
        const float fB = (float)((r >> 11) & 63);   // BS antenna index

        // Closed-form mean and mean-of-squares over d.
        const float d_ = fmaf(G[3], fB, fmaf(G[4], fU, fmaf(G[5], fS, G[6])));
        const float e_ = fmaf(G[7], fB, fmaf(G[8], fU, fmaf(G[9], fS, G[10])));
        const float f_ = fmaf(fB, fmaf(G[11], fB, fmaf(G[14], fU, fmaf(G[15], fS, G[17]))),
                         fmaf(fU, fmaf(G[12], fU, fmaf(G[16], fS, G[18])),
                         fmaf(fS, fmaf(G[13], fS, G[19]), G[20])));
        const float meanSq = fmaf(re, fmaf(G[0], re, fmaf(G[2], im, d_)),
                             fmaf(im, fmaf(G[1], im, e_), f_));
        const float mu = fmaf(G[21], re, fmaf(G[22], im,
                         fmaf(G[23], fB, fmaf(G[24], fU, fmaf(G[25], fS, G[26])))));
        const float var  = fmaf(-mu, mu, meanSq);
        const float rstd = rsqrtf(var + LN_EPS);

        float4 o;
#pragma unroll
        for (int j = 0; j < 4; ++j) {
            float t = bsum[j];
            t = fmaf(fS, wfv[j], t);
            t = fmaf(fU, wuv[j], t);
            t = fmaf(fB, wsv[j], t);
            t = fmaf(im, wc1[j], t);
            t = fmaf(re, wc0[j], t);
            const float y = fmaf((t - mu) * rstd, gv[j], bv[j]);
            (&o.x)[j] = y;
        }
        *reinterpret_cast<float4*>(out + (size_t)r * D_MODEL + d0) = o;
    }
}

extern "C" void kernel_launch(void* const* d_in, const int* in_sizes, int n_in,
                              void* d_out, int out_size, void* d_ws, size_t ws_size,
                              hipStream_t stream) {
    const float* csi_real = (const float*)d_in[0];
    const float* csi_imag = (const float*)d_in[1];
    const float* w_c      = (const float*)d_in[2];
    const float* b_c      = (const float*)d_in[3];
    const float* w_s      = (const float*)d_in[4];
    const float* b_s      = (const float*)d_in[5];
    const float* w_u      = (const float*)d_in[6];
    const float* b_u      = (const float*)d_in[7];
    const float* w_f      = (const float*)d_in[8];
    const float* b_f      = (const float*)d_in[9];
    const float* ln_gamma = (const float*)d_in[10];
    const float* ln_beta  = (const float*)d_in[11];
    float* out = (float*)d_out;
    float* g   = (float*)d_ws;   // 27 floats of scratch

    csi_gram_kernel<<<1, 64, 0, stream>>>(w_c, b_c, w_s, b_s, w_u, b_u, w_f, b_f, g);

    const int blocks = 2048;   // 8192 waves, 64 rows each
    csi_encoder_kernel<<<blocks, 256, 0, stream>>>(
        csi_real, csi_imag, w_c, b_c, w_s, b_s, w_u, b_u, w_f, b_f,
        ln_gamma, ln_beta, g, out);
}

// Round 5
// 118.882 us; speedup vs baseline: 1.2428x; 1.2169x over previous
//
#include <hip/hip_runtime.h>

#define D_MODEL 256
#define N_ROWS (4 * 64 * 4 * 512)   // 524288 rows of D=256
#define LN_EPS 1e-5f

// ---------------------------------------------------------------------------
// Kernel A: one wave computes the 6x6 Gram matrix (and column means) of the
// per-d weight vectors a(d) = [wc0, wc1, ws, wu, wf, bsum], in double, so the
// main kernel can evaluate mean and E[x^2] per row in closed form.
// Output g[27] (all pre-divided by 256, cross terms pre-doubled):
//  0:rr 1:ii 2:2ri | 3..6: 2*r{B,U,S,1} | 7..10: 2*i{B,U,S,1}
//  11:BB 12:UU 13:SS 14:2BU 15:2BS 16:2US 17:2B 18:2U 19:2S 20:11
//  21..26: means of a_i
// ---------------------------------------------------------------------------
__global__ __launch_bounds__(64) void csi_gram_kernel(
    const float* __restrict__ w_c, const float* __restrict__ b_c,
    const float* __restrict__ w_s, const float* __restrict__ b_s,
    const float* __restrict__ w_u, const float* __restrict__ b_u,
    const float* __restrict__ w_f, const float* __restrict__ b_f,
    float* __restrict__ g)
{
    const int lane = threadIdx.x;
    double acc[27];
#pragma unroll
    for (int i = 0; i < 27; ++i) acc[i] = 0.0;

#pragma unroll
    for (int k = 0; k < 4; ++k) {
        const int d = lane + 64 * k;
        const double a0 = w_c[2 * d];
        const double a1 = w_c[2 * d + 1];
        const double a2 = w_s[d];
        const double a3 = w_u[d];
        const double a4 = w_f[d];
        const double a5 = (double)b_c[d] + (double)b_s[d] + (double)b_u[d] + (double)b_f[d];
        acc[0]  += a0 * a0;  acc[1]  += a1 * a1;  acc[2]  += a0 * a1;
        acc[3]  += a0 * a2;  acc[4]  += a0 * a3;  acc[5]  += a0 * a4;  acc[6]  += a0 * a5;
        acc[7]  += a1 * a2;  acc[8]  += a1 * a3;  acc[9]  += a1 * a4;  acc[10] += a1 * a5;
        acc[11] += a2 * a2;  acc[12] += a3 * a3;  acc[13] += a4 * a4;
        acc[14] += a2 * a3;  acc[15] += a2 * a4;  acc[16] += a3 * a4;
        acc[17] += a2 * a5;  acc[18] += a3 * a5;  acc[19] += a4 * a5;  acc[20] += a5 * a5;
        acc[21] += a0;  acc[22] += a1;  acc[23] += a2;
        acc[24] += a3;  acc[25] += a4;  acc[26] += a5;
    }

#pragma unroll
    for (int off = 32; off >= 1; off >>= 1) {
#pragma unroll
        for (int i = 0; i < 27; ++i) acc[i] += __shfl_xor(acc[i], off, 64);
    }

    if (lane == 0) {
        const double inv = 1.0 / 256.0;
        double r[27];
#pragma unroll
        for (int i = 0; i < 27; ++i) r[i] = acc[i] * inv;
        // Cross terms doubled — explicit, auditable list: {2..10, 14..19}.
        r[2]  *= 2.0; r[3]  *= 2.0; r[4]  *= 2.0; r[5]  *= 2.0; r[6]  *= 2.0;
        r[7]  *= 2.0; r[8]  *= 2.0; r[9]  *= 2.0; r[10] *= 2.0;
        r[14] *= 2.0; r[15] *= 2.0; r[16] *= 2.0;
        r[17] *= 2.0; r[18] *= 2.0; r[19] *= 2.0;
#pragma unroll
        for (int i = 0; i < 27; ++i) g[i] = (float)r[i];
    }
}

// ---------------------------------------------------------------------------
// Kernel B: streaming with scalar-path CSI loads.
// Each wave owns a CONTIGUOUS 64-row chunk; csi[r] is wave-uniform, fetched
// via s_load (lgkmcnt) so the loop has NO vector loads -> no vmcnt waits ->
// global stores pipeline deep (fill-kernel style).
// Chunk = 64 rows divides SC=512, so ue/bs indices are per-wave constants.
// ---------------------------------------------------------------------------
__global__ __launch_bounds__(256) void csi_encoder_kernel(
    const float* __restrict__ csi_real,
    const float* __restrict__ csi_imag,
    const float* __restrict__ w_c,
    const float* __restrict__ b_c,
    const float* __restrict__ w_s,
    const float* __restrict__ b_s,
    const float* __restrict__ w_u,
    const float* __restrict__ b_u,
    const float* __restrict__ w_f,
    const float* __restrict__ b_f,
    const float* __restrict__ ln_gamma,
    const float* __restrict__ ln_beta,
    const float* __restrict__ g,       // 27 Gram/mean constants
    float* __restrict__ out)
{
    const int lane = threadIdx.x & 63;
    const int waveId = blockIdx.x * 4 + (threadIdx.x >> 6);   // 0..8191
    // Wave-uniform chunk base, forced into an SGPR.
    const int rbase = __builtin_amdgcn_readfirstlane(waveId * 64);

    // Per-wave constants.
    const int s0i = rbase & 511;
    const float fU = (float)((rbase >> 9) & 3);
    const float fB = (float)((rbase >> 11) & 63);

    // Gram constants (uniform pointer, constant indices -> scalar loads).
    const float G0 = g[0],  G1 = g[1],  G2 = g[2];
    const float G3 = g[3],  G4 = g[4],  G5 = g[5],  G6 = g[6];
    const float G7 = g[7],  G8 = g[8],  G9 = g[9],  G10 = g[10];
    const float G11 = g[11], G12 = g[12], G13 = g[13];
    const float G14 = g[14], G15 = g[15], G16 = g[16];
    const float G17 = g[17], G18 = g[18], G19 = g[19], G20 = g[20];
    const float G21 = g[21], G22 = g[22], G23 = g[23];
    const float G24 = g[24], G25 = g[25], G26 = g[26];

    // Fold fB, fU into per-wave scalars.
    const float cR  = fmaf(G3, fB, fmaf(G4, fU, G6));     // re coefficient tail
    const float cI  = fmaf(G7, fB, fmaf(G8, fU, G10));    // im coefficient tail
    const float cS1 = fmaf(G15, fB, fmaf(G16, fU, G19));  // linear-in-fS tail
    const float cS0 = fmaf(fB, fmaf(G11, fB, fmaf(G14, fU, G17)),
                      fmaf(fU, fmaf(G12, fU, G18), G20)); // constant tail
    const float cM  = fmaf(G23, fB, fmaf(G24, fU, G26));  // mean tail

    // Per-lane (per-d) constants; fold fB, fU into the bias.
    const int d0 = lane * 4;
    float wc0[4], wc1[4], wfv[4], base[4], gv[4], bv[4];
#pragma unroll
    for (int j = 0; j < 4; ++j) {
        const int d = d0 + j;
        wc0[j] = w_c[d * 2 + 0];
        wc1[j] = w_c[d * 2 + 1];
        wfv[j] = w_f[d];
        const float bsum = b_c[d] + b_s[d] + b_u[d] + b_f[d];
        base[j] = fmaf(fB, w_s[d], fmaf(fU, w_u[d], bsum));
        gv[j]  = ln_gamma[d];
        bv[j]  = ln_beta[d];
    }

    // Uniform scalar base pointers for the CSI chunk.
    const float* __restrict__ cr = csi_real + rbase;
    const float* __restrict__ ci = csi_imag + rbase;
    float* __restrict__ op = out + (size_t)rbase * D_MODEL + d0;

#pragma unroll 8
    for (int j = 0; j < 64; ++j) {
        const float re = cr[j];              // s_load (lgkmcnt)
        const float im = ci[j];              // s_load (lgkmcnt)
        const float fS = (float)(s0i + j);

        const float mu = fmaf(G21, re, fmaf(G22, im, fmaf(G25, fS, cM)));
        const float ms = fmaf(re, fmaf(G0, re, fmaf(G2, im, fmaf(G5, fS, cR))),
                         fmaf(im, fmaf(G1, im, fmaf(G9, fS, cI)),
                         fmaf(fS, fmaf(G13, fS, cS1), cS0)));
        const float var  = fmaf(-mu, mu, ms);
        const float rstd = rsqrtf(var + LN_EPS);

        float4 o;
#pragma unroll
        for (int k = 0; k < 4; ++k) {
            const float t = fmaf(re, wc0[k], fmaf(im, wc1[k],
                             fmaf(fS, wfv[k], base[k])));
            (&o.x)[k] = fmaf((t - mu) * rstd, gv[k], bv[k]);
        }
        *reinterpret_cast<float4*>(op + (size_t)j * D_MODEL) = o;
    }
}

extern "C" void kernel_launch(void* const* d_in, const int* in_sizes, int n_in,
                              void* d_out, int out_size, void* d_ws, size_t ws_size,
                              hipStream_t stream) {
    const float* csi_real = (const float*)d_in[0];
    const float* csi_imag = (const float*)d_in[1];
    const float* w_c      = (const float*)d_in[2];
    const float* b_c      = (const float*)d_in[3];
    const float* w_s      = (const float*)d_in[4];
    const float* b_s      = (const float*)d_in[5];
    const float* w_u      = (const float*)d_in[6];
    const float* b_u      = (const float*)d_in[7];
    const float* w_f      = (const float*)d_in[8];
    const float* b_f      = (const float*)d_in[9];
    const float* ln_gamma = (const float*)d_in[10];
    const float* ln_beta  = (const float*)d_in[11];
    float* out = (float*)d_out;
    float* g   = (float*)d_ws;   // 27 floats of scratch

    csi_gram_kernel<<<1, 64, 0, stream>>>(w_c, b_c, w_s, b_s, w_u, b_u, w_f, b_f, g);

    // 2048 blocks x 4 waves = 8192 waves; each owns a contiguous 64-row chunk.
    csi_encoder_kernel<<<2048, 256, 0, stream>>>(
        csi_real, csi_imag, w_c, b_c, w_s, b_s, w_u, b_u, w_f, b_f,
        ln_gamma, ln_beta, g, out);
}

// Round 6
// 103.051 us; speedup vs baseline: 1.4338x; 1.1536x over previous
//
#include <hip/hip_runtime.h>

#define D_MODEL 256
#define LN_EPS 1e-5f

typedef float f4 __attribute__((ext_vector_type(4)));

// ---------------------------------------------------------------------------
// Single fused kernel. Each wave owns a contiguous 64-row chunk (64 = SC tile,
// so fU/fB are per-wave constants). Per row: x[d] = a0*re + a1*im + a2*fS + w,
// where w(d) = fB*ws + fU*wu + (bc+bs+bu+bf) folds the wave constants.
// LayerNorm mean/var come from the 4x4 Gram of (a0,a1,a2,w) + the 4 means,
// computed per-wave with ONE 14-value butterfly (no LDS, no second kernel).
// Main loop has no vector loads (CSI via uniform s_load path) and uses
// nontemporal stores so the 512 MB output stream skips L2 allocation.
// ---------------------------------------------------------------------------
__global__ __launch_bounds__(256) void csi_encoder_kernel(
    const float* __restrict__ csi_real,
    const float* __restrict__ csi_imag,
    const float* __restrict__ w_c,
    const float* __restrict__ b_c,
    const float* __restrict__ w_s,
    const float* __restrict__ b_s,
    const float* __restrict__ w_u,
    const float* __restrict__ b_u,
    const float* __restrict__ w_f,
    const float* __restrict__ b_f,
    const float* __restrict__ ln_gamma,
    const float* __restrict__ ln_beta,
    float* __restrict__ out)
{
    const int lane = threadIdx.x & 63;
    const int waveId = blockIdx.x * 4 + (threadIdx.x >> 6);   // 0..8191
    const int rbase = __builtin_amdgcn_readfirstlane(waveId * 64);

    const int s0i = rbase & 511;                 // starting subcarrier index
    const float fU = (float)((rbase >> 9) & 3);
    const float fB = (float)((rbase >> 11) & 63);

    // Per-lane (per-d) constants for d = d0..d0+3.
    const int d0 = lane * 4;
    float a0[4], a1[4], a2[4], wv[4], gv[4], bv[4];
#pragma unroll
    for (int j = 0; j < 4; ++j) {
        const int d = d0 + j;
        a0[j] = w_c[d * 2 + 0];
        a1[j] = w_c[d * 2 + 1];
        a2[j] = w_f[d];
        const float bsum = b_c[d] + b_s[d] + b_u[d] + b_f[d];
        wv[j] = fmaf(fB, w_s[d], fmaf(fU, w_u[d], bsum));
        gv[j] = ln_gamma[d];
        bv[j] = ln_beta[d];
    }

    // 14 sums over d: 4x4 Gram (10) + means (4) of h = (a0, a1, a2, w).
    float p[14];
#pragma unroll
    for (int i = 0; i < 14; ++i) p[i] = 0.0f;
#pragma unroll
    for (int j = 0; j < 4; ++j) {
        p[0]  = fmaf(a0[j], a0[j], p[0]);
        p[1]  = fmaf(a1[j], a1[j], p[1]);
        p[2]  = fmaf(a2[j], a2[j], p[2]);
        p[3]  = fmaf(wv[j], wv[j], p[3]);
        p[4]  = fmaf(a0[j], a1[j], p[4]);
        p[5]  = fmaf(a0[j], a2[j], p[5]);
        p[6]  = fmaf(a0[j], wv[j], p[6]);
        p[7]  = fmaf(a1[j], a2[j], p[7]);
        p[8]  = fmaf(a1[j], wv[j], p[8]);
        p[9]  = fmaf(a2[j], wv[j], p[9]);
        p[10] += a0[j];
        p[11] += a1[j];
        p[12] += a2[j];
        p[13] += wv[j];
    }
#pragma unroll
    for (int off = 32; off >= 1; off >>= 1) {
#pragma unroll
        for (int i = 0; i < 14; ++i) p[i] += __shfl_xor(p[i], off, 64);
    }

    const float inv = 1.0f / 256.0f;
    const float E00 = p[0] * inv,  E11 = p[1] * inv,  E22 = p[2] * inv;
    const float E33 = p[3] * inv;
    const float F01 = 2.0f * p[4] * inv, F02 = 2.0f * p[5] * inv;
    const float F03 = 2.0f * p[6] * inv, F12 = 2.0f * p[7] * inv;
    const float F13 = 2.0f * p[8] * inv, F23 = 2.0f * p[9] * inv;
    const float M0 = p[10] * inv, M1 = p[11] * inv;
    const float M2 = p[12] * inv, M3 = p[13] * inv;

    // Uniform base pointers for this wave's chunk.
    const float* __restrict__ cr = csi_real + rbase;
    const float* __restrict__ ci = csi_imag + rbase;
    float* __restrict__ op = out + (size_t)rbase * D_MODEL + d0;

#pragma unroll 8
    for (int j = 0; j < 64; ++j) {
        const float re = cr[j];              // uniform -> s_load (lgkmcnt)
        const float im = ci[j];              // uniform -> s_load (lgkmcnt)
        const float fS = (float)(s0i + j);

        const float mu = fmaf(M0, re, fmaf(M1, im, fmaf(M2, fS, M3)));
        const float ms = fmaf(re, fmaf(E00, re, fmaf(F01, im, fmaf(F02, fS, F03))),
                         fmaf(im, fmaf(E11, im, fmaf(F12, fS, F13)),
                         fmaf(fS, fmaf(E22, fS, F23), E33)));
        const float var  = fmaf(-mu, mu, ms);
        const float rstd = rsqrtf(var + LN_EPS);

        f4 o;
#pragma unroll
        for (int k = 0; k < 4; ++k) {
            const float t = fmaf(re, a0[k], fmaf(im, a1[k], fmaf(fS, a2[k], wv[k])));
            o[k] = fmaf((t - mu) * rstd, gv[k], bv[k]);
        }
        __builtin_nontemporal_store(o, (f4*)(op + (size_t)j * D_MODEL));
    }
}

extern "C" void kernel_launch(void* const* d_in, const int* in_sizes, int n_in,
                              void* d_out, int out_size, void* d_ws, size_t ws_size,
                              hipStream_t stream) {
    const float* csi_real = (const float*)d_in[0];
    const float* csi_imag = (const float*)d_in[1];
    const float* w_c      = (const float*)d_in[2];
    const float* b_c      = (const float*)d_in[3];
    const float* w_s      = (const float*)d_in[4];
    const float* b_s      = (const float*)d_in[5];
    const float* w_u      = (const float*)d_in[6];
    const float* b_u      = (const float*)d_in[7];
    const float* w_f      = (const float*)d_in[8];
    const float* b_f      = (const float*)d_in[9];
    const float* ln_gamma = (const float*)d_in[10];
    const float* ln_beta  = (const float*)d_in[11];
    float* out = (float*)d_out;

    // 2048 blocks x 4 waves = 8192 waves; each owns a contiguous 64-row chunk.
    csi_encoder_kernel<<<2048, 256, 0, stream>>>(
        csi_real, csi_imag, w_c, b_c, w_s, b_s, w_u, b_u, w_f, b_f,
        ln_gamma, ln_beta, out);
}